// Round 17
// baseline (923.364 us; speedup 1.0000x reference)
//
#include <hip/hip_runtime.h>
#include <hip/hip_bf16.h>
#include <math.h>

typedef __bf16 bf16_t;
typedef __bf16 bf16x4 __attribute__((ext_vector_type(4)));
typedef __bf16 bf16x8 __attribute__((ext_vector_type(8)));
typedef float  f32x4  __attribute__((ext_vector_type(4)));

#define DIN   3072
#define NOUT  24576
#define HALF  12288
#define MTOK  4096
#define BM    128
#define BN    128
#define BK    64
#define NT    48          // DIN / BK

// fused-prepass block ranges (small kernels first: overlap under quant_w's body)
#define NB_LORA  (MTOK / 8)                       // 512
#define NB_QX    (MTOK)                           // 4096
#define NB_CVT   (NOUT * 32 / 4 / 256)            // 768
#define NB_QW    (NOUT * (DIN / 4) / 256)         // 73728
#define B0       (NB_LORA)
#define B1       (B0 + NB_QX)
#define B2       (B1 + NB_CVT)
#define NB_PREP  (B2 + NB_QW)

#define GLD16(gp, lp) \
    __builtin_amdgcn_global_load_lds((const __attribute__((address_space(1))) void*)(gp), \
                                     (__attribute__((address_space(3))) void*)(lp), 16, 0, 0)

#define BAR()    __builtin_amdgcn_s_barrier()
#define LGKM0()  asm volatile("s_waitcnt lgkmcnt(0)" ::: "memory")
#define WAITV(N) asm volatile("s_waitcnt vmcnt(" #N ")" ::: "memory")
#define SCHED0() __builtin_amdgcn_sched_barrier(0)

// ---------------- fused prepass: lora_t | quant_x | cvt_lu | quant_w --------------
__global__ __launch_bounds__(256) void k_prep(const float* __restrict__ x,
                                              const float* __restrict__ w,
                                              const float* __restrict__ ld,
                                              const float* __restrict__ lu,
                                              bf16_t* __restrict__ xq,
                                              bf16_t* __restrict__ wq,
                                              bf16_t* __restrict__ T,
                                              bf16_t* __restrict__ lub) {
    const int bid = blockIdx.x;
    const int t = threadIdx.x;

    if (bid < B0) {
        // ---- T = x @ lora_down^T (full-precision x), 8 tokens x 32 ranks ----
        int r = t & 31;
        int m = bid * 8 + (t >> 5);
        const float4* xr = reinterpret_cast<const float4*>(x + (size_t)m * DIN);
        const float4* lr = reinterpret_cast<const float4*>(ld + (size_t)r * DIN);
        float acc = 0.f;
#pragma unroll 4
        for (int i = 0; i < DIN / 4; ++i) {
            float4 a = xr[i], b = lr[i];
            acc += a.x * b.x + a.y * b.y + a.z * b.z + a.w * b.w;
        }
        T[(size_t)m * 32 + r] = (bf16_t)acc;
    } else if (bid < B1) {
        // ---- per-token activation int4 fake-quant -> bf16 ----
        int m = bid - B0;
        const float4* row = reinterpret_cast<const float4*>(x + (size_t)m * DIN);
        float4 v[3];
        float vm = 0.f;
#pragma unroll
        for (int i = 0; i < 3; ++i) {
            v[i] = row[t + i * 256];
            vm = fmaxf(vm, fmaxf(fmaxf(fabsf(v[i].x), fabsf(v[i].y)),
                                 fmaxf(fabsf(v[i].z), fabsf(v[i].w))));
        }
#pragma unroll
        for (int d = 1; d < 64; d <<= 1) vm = fmaxf(vm, __shfl_xor(vm, d));
        __shared__ float sm[4];
        if ((t & 63) == 0) sm[t >> 6] = vm;
        __syncthreads();
        vm = fmaxf(fmaxf(sm[0], sm[1]), fmaxf(sm[2], sm[3]));
        float s = fmaxf(vm * (1.f / 7.f), 1e-8f);
        float inv = 1.f / s;
        bf16x4* orow = reinterpret_cast<bf16x4*>(xq + (size_t)m * DIN);
#pragma unroll
        for (int i = 0; i < 3; ++i) {
            bf16x4 o;
            o[0] = (bf16_t)(fminf(fmaxf(rintf(v[i].x * inv), -8.f), 7.f) * s);
            o[1] = (bf16_t)(fminf(fmaxf(rintf(v[i].y * inv), -8.f), 7.f) * s);
            o[2] = (bf16_t)(fminf(fmaxf(rintf(v[i].z * inv), -8.f), 7.f) * s);
            o[3] = (bf16_t)(fminf(fmaxf(rintf(v[i].w * inv), -8.f), 7.f) * s);
            orow[t + i * 256] = o;
        }
    } else if (bid < B2) {
        // ---- cast lora_up f32 -> bf16 ----
        size_t idx = (size_t)(bid - B1) * 256 + t;
        float4 v = reinterpret_cast<const float4*>(lu)[idx];
        bf16x4 o;
        o[0] = (bf16_t)v.x; o[1] = (bf16_t)v.y; o[2] = (bf16_t)v.z; o[3] = (bf16_t)v.w;
        reinterpret_cast<bf16x4*>(lub)[idx] = o;
    } else {
        // ---- per-(row, group-of-64) weight int4 fake-quant -> bf16 ----
        size_t idx = (size_t)(bid - B2) * 256 + t;   // f32x4 index
        f32x4 v = __builtin_nontemporal_load(reinterpret_cast<const f32x4*>(w) + idx);
        float vm = fmaxf(fmaxf(fabsf(v[0]), fabsf(v[1])), fmaxf(fabsf(v[2]), fabsf(v[3])));
        vm = fmaxf(vm, __shfl_xor(vm, 1));
        vm = fmaxf(vm, __shfl_xor(vm, 2));
        vm = fmaxf(vm, __shfl_xor(vm, 4));
        vm = fmaxf(vm, __shfl_xor(vm, 8));
        float s = fmaxf(vm * (1.f / 7.f), 1e-8f);
        float inv = 1.f / s;
        bf16x4 o;
        o[0] = (bf16_t)(fminf(fmaxf(rintf(v[0] * inv), -8.f), 7.f) * s);
        o[1] = (bf16_t)(fminf(fmaxf(rintf(v[1] * inv), -8.f), 7.f) * s);
        o[2] = (bf16_t)(fminf(fmaxf(rintf(v[2] * inv), -8.f), 7.f) * s);
        o[3] = (bf16_t)(fminf(fmaxf(rintf(v[3] * inv), -8.f), 7.f) * s);
        reinterpret_cast<bf16x4*>(wq)[idx] = o;
    }
}

// ---------------- K4: B-dbuf + A-reg-prefetch fused GEMM, 2 blocks/CU -------------
// r15 geometry (BM=BN=128, BK=64, 8 waves H/G, 32 MFMA/barrier, 2 BAR/tile),
// with every DMA drain COVERED:
//   top:   stage B(t+1)->B^1 (4 gld; covered by whole tile)
//   then:  read A-frags sA->regs (8 ds_read), lgkm0, BAR#1 (sA free)
//   then:  stage A(t+1)->sA (2 gld; covered by B-reads + MFMA burst)
//   then:  B-frag reads + 32 MFMA, WAITV(0) (all covered), BAR#2
// LDS: sA 16K | B0 32K | B1 32K = 80K -> exactly 2 blocks/CU.
__global__ __launch_bounds__(512, 4) void k_gemm(const bf16_t* __restrict__ xq,
                                                 const bf16_t* __restrict__ wq,
                                                 const bf16_t* __restrict__ T,
                                                 const bf16_t* __restrict__ lub,
                                                 float* __restrict__ out) {
    __shared__ __align__(16) char smem[81920];   // sA 16K | B dbuf 64K; exch 64K

    int tid = threadIdx.x, lane = tid & 63, w = tid >> 6;
    int half = w >> 2;                 // 0 = H, 1 = G
    int wr = (w & 3) >> 1, wc = w & 1;
    const int l15 = lane & 15, lhi = lane >> 4;

    // XCD-bijective swizzle (grid 3072 % 8 == 0)
    int nwg = gridDim.x;
    int cpx = nwg >> 3;
    int swz = (blockIdx.x & 7) * cpx + (blockIdx.x >> 3);
    int mt = swz & 31, nt = swz >> 5;  // mt fast: neighbors share B panels
    int m0 = mt * BM, c0 = nt * BN;

    f32x4 acc[4][4];
#pragma unroll
    for (int i = 0; i < 4; ++i)
#pragma unroll
        for (int j = 0; j < 4; ++j) acc[i][j] = (f32x4){0.f, 0.f, 0.f, 0.f};

    // hoisted staging pointers (both-sides swizzle folded into source).
    // A: 1024 chunks, 2/thread (chunks tid, tid+512). B: BH 1024 + BG 1024,
    // 4/thread (BH: tid, tid+512; BG: same rows at c0+HALF).
    const bf16_t *pA0, *pA1, *pH0, *pH1, *pG0, *pG1;
    {
        int c_lo = tid, c_hi = tid + 512;
        int r_lo = c_lo >> 3, r_hi = c_hi >> 3;
        int g_lo = ((c_lo & 7) ^ (r_lo & 7)) * 8;
        int g_hi = ((c_hi & 7) ^ (r_hi & 7)) * 8;
        pA0 = xq + (size_t)(m0 + r_lo) * DIN + g_lo;
        pA1 = xq + (size_t)(m0 + r_hi) * DIN + g_hi;
        pH0 = wq + (size_t)(c0 + r_lo) * DIN + g_lo;
        pH1 = wq + (size_t)(c0 + r_hi) * DIN + g_hi;
        pG0 = pH0 + (size_t)HALF * DIN;
        pG1 = pH1 + (size_t)HALF * DIN;
    }
    char* const sA = (char*)smem;
    const int dst_lo = tid * 16, dst_hi = (tid + 512) * 16;

#define STAGE_B(nb)                                                           \
    do {                                                                      \
        GLD16(pH0, (nb) + dst_lo);         GLD16(pH1, (nb) + dst_hi);         \
        GLD16(pG0, (nb) + 16384 + dst_lo); GLD16(pG1, (nb) + 16384 + dst_hi); \
    } while (0)
#define STAGE_A()                                                             \
    do {                                                                      \
        GLD16(pA0, sA + dst_lo);           GLD16(pA1, sA + dst_hi);           \
    } while (0)

    // ---- prologue: stage tile 0 (A -> sA, B -> B0) ----
    STAGE_A();
    STAGE_B((char*)smem + 16384);
    pA0 += BK; pA1 += BK; pH0 += BK; pH1 += BK; pG0 += BK; pG1 += BK;
    WAITV(0);
    BAR();
    SCHED0();

    for (int t = 0; t < NT; ++t) {
        const char* cB = (const char*)smem + 16384 + (t & 1) * 32768;
        char* nB = (char*)smem + 16384 + ((t + 1) & 1) * 32768;

        // stage next B early (covered by the whole tile)
        STAGE_B(nB);

        // A-frag register prefetch from sA
        bf16x8 a[4][2];
#pragma unroll
        for (int ks = 0; ks < 2; ++ks) {
            int c16 = ks * 4 + lhi;
#pragma unroll
            for (int i = 0; i < 4; ++i) {
                int ra = wr * 64 + i * 16 + l15;
                a[i][ks] = *reinterpret_cast<const bf16x8*>(sA + ra * 128 + ((c16 ^ (ra & 7)) << 4));
            }
        }
        LGKM0();
        BAR();            // #1: all waves' A-reads done -> sA free for overwrite
        SCHED0();

        // stage next A into sA (covered by B-reads + MFMA burst below)
        STAGE_A();

        // B-frag reads + MFMA
        const char* sB = cB + (half << 14);
#pragma unroll
        for (int ks = 0; ks < 2; ++ks) {
            int c16 = ks * 4 + lhi;
            bf16x8 b[4];
#pragma unroll
            for (int i = 0; i < 4; ++i) {
                int rb = wc * 64 + i * 16 + l15;
                b[i] = *reinterpret_cast<const bf16x8*>(sB + rb * 128 + ((c16 ^ (rb & 7)) << 4));
            }
#pragma unroll
            for (int m = 0; m < 4; ++m)
#pragma unroll
                for (int n = 0; n < 4; ++n)
                    acc[m][n] = __builtin_amdgcn_mfma_f32_16x16x32_bf16(a[m][ks], b[n], acc[m][n], 0, 0, 0);
        }

        WAITV(0);         // covered: B issued a tile ago, A issued before MFMA burst
        BAR();            // #2: cross-wave visibility for tile t+1
        SCHED0();

        const int adv = (t + 2 < NT) ? BK : 0;   // clamp: last iter re-stages NT-1
        pA0 += adv; pA1 += adv; pH0 += adv; pH1 += adv; pG0 += adv; pG1 += adv;
    }

    // ---- LoRA correction: one K=32 MFMA per fragment (RANK == 32) ----
    {
        bf16x8 tf[4];
#pragma unroll
        for (int m = 0; m < 4; ++m)
            tf[m] = *reinterpret_cast<const bf16x8*>(
                T + (size_t)(m0 + wr * 64 + m * 16 + l15) * 32 + lhi * 8);
#pragma unroll
        for (int n = 0; n < 4; ++n) {
            bf16x8 lu = *reinterpret_cast<const bf16x8*>(
                lub + (size_t)(c0 + half * HALF + wc * 64 + n * 16 + l15) * 32 + lhi * 8);
#pragma unroll
            for (int m = 0; m < 4; ++m)
                acc[m][n] = __builtin_amdgcn_mfma_f32_16x16x32_bf16(tf[m], lu, acc[m][n], 0, 0, 0);
        }
    }

    // ---- GEGLU epilogue: exch gl -> in-place product -> coalesced nt stores ----
    __syncthreads();                    // staging drained by final WAITV+BAR
    float* exch = (float*)smem;         // [128][128] f32, col XOR-swizzled
    if (half) {
#pragma unroll
        for (int m = 0; m < 4; ++m)
#pragma unroll
            for (int n = 0; n < 4; ++n) {
                int col = wc * 64 + n * 16 + l15;
#pragma unroll
                for (int r = 0; r < 4; ++r) {
                    int row = wr * 64 + m * 16 + lhi * 4 + r;
                    float g = acc[m][n][r];
                    float gl = 0.5f * g * (1.0f + erff(g * 0.70710678118654752f));
                    exch[row * 128 + (col ^ (((row >> 2) & 3) << 4))] = gl;
                }
            }
    }
    __syncthreads();
    if (!half) {
        // in-place: each slot read+written by exactly one lane
#pragma unroll
        for (int m = 0; m < 4; ++m)
#pragma unroll
            for (int n = 0; n < 4; ++n) {
                int col = wc * 64 + n * 16 + l15;
#pragma unroll
                for (int r = 0; r < 4; ++r) {
                    int row = wr * 64 + m * 16 + lhi * 4 + r;
                    int sidx = row * 128 + (col ^ (((row >> 2) & 3) << 4));
                    exch[sidx] = acc[m][n][r] * exch[sidx];
                }
            }
    }
    __syncthreads();
    // all 8 waves: stream 64 KB out, 16B/lane coalesced, full-line nt writes
#pragma unroll
    for (int i = 0; i < 8; ++i) {
        int idx = i * 512 + tid;        // f32x4 chunk id, 4096 total
        int row = idx >> 5;             // 32 chunks per 128-col row
        int c4 = idx & 31;
        f32x4 v = *reinterpret_cast<const f32x4*>(
            exch + row * 128 + ((c4 ^ (((row >> 2) & 3) << 2)) << 2));
        __builtin_nontemporal_store(v, reinterpret_cast<f32x4*>(
            out + (size_t)(m0 + row) * HALF + c0 + c4 * 4));
    }
#undef STAGE_B
#undef STAGE_A
}

extern "C" void kernel_launch(void* const* d_in, const int* in_sizes, int n_in,
                              void* d_out, int out_size, void* d_ws, size_t ws_size,
                              hipStream_t stream) {
    const float* x  = (const float*)d_in[0];   // [1,4096,3072]
    const float* wr = (const float*)d_in[1];   // [24576,3072]
    const float* ld = (const float*)d_in[2];   // [32,3072]
    const float* lu = (const float*)d_in[3];   // [24576,32]
    float* out = (float*)d_out;                // [4096,12288] f32

    bf16_t* xq  = (bf16_t*)d_ws;
    bf16_t* wq  = xq + (size_t)MTOK * DIN;
    bf16_t* T   = wq + (size_t)NOUT * DIN;
    bf16_t* lub = T  + (size_t)MTOK * 32;

    k_prep<<<NB_PREP, 256, 0, stream>>>(x, wr, ld, lu, xq, wq, T, lub);
    k_gemm<<<(MTOK / BM) * (HALF / BN), 512, 0, stream>>>(xq, wq, T, lub, out);
}

// Round 18
// 755.369 us; speedup vs baseline: 1.2224x; 1.2224x over previous
//
#include <hip/hip_runtime.h>
#include <hip/hip_bf16.h>
#include <math.h>

typedef __bf16 bf16_t;
typedef __bf16 bf16x4 __attribute__((ext_vector_type(4)));
typedef __bf16 bf16x8 __attribute__((ext_vector_type(8)));
typedef float  f32x4  __attribute__((ext_vector_type(4)));

#define DIN   3072
#define NOUT  24576
#define HALF  12288
#define MTOK  4096
#define BM    128
#define BN    128
#define BK    64

// fused-prepass block ranges (small kernels first: overlap under quant_w's body)
#define NB_LORA  (MTOK / 8)                       // 512
#define NB_QX    (MTOK)                           // 4096
#define NB_CVT   (NOUT * 32 / 4 / 256)            // 768
#define NB_QW    (NOUT * (DIN / 4) / 256)         // 73728
#define B0       (NB_LORA)
#define B1       (B0 + NB_QX)
#define B2       (B1 + NB_CVT)
#define NB_PREP  (B2 + NB_QW)

#define GLD16(gp, lp) \
    __builtin_amdgcn_global_load_lds((const __attribute__((address_space(1))) void*)(gp), \
                                     (__attribute__((address_space(3))) void*)(lp), 16, 0, 0)

// ---------------- fused prepass: lora_t | quant_x | cvt_lu | quant_w --------------
__global__ __launch_bounds__(256) void k_prep(const float* __restrict__ x,
                                              const float* __restrict__ w,
                                              const float* __restrict__ ld,
                                              const float* __restrict__ lu,
                                              bf16_t* __restrict__ xq,
                                              bf16_t* __restrict__ wq,
                                              bf16_t* __restrict__ T,
                                              bf16_t* __restrict__ lub) {
    const int bid = blockIdx.x;
    const int t = threadIdx.x;

    if (bid < B0) {
        // ---- T = x @ lora_down^T (full-precision x), 8 tokens x 32 ranks ----
        int r = t & 31;
        int m = bid * 8 + (t >> 5);
        const float4* xr = reinterpret_cast<const float4*>(x + (size_t)m * DIN);
        const float4* lr = reinterpret_cast<const float4*>(ld + (size_t)r * DIN);
        float acc = 0.f;
#pragma unroll 4
        for (int i = 0; i < DIN / 4; ++i) {
            float4 a = xr[i], b = lr[i];
            acc += a.x * b.x + a.y * b.y + a.z * b.z + a.w * b.w;
        }
        T[(size_t)m * 32 + r] = (bf16_t)acc;
    } else if (bid < B1) {
        // ---- per-token activation int4 fake-quant -> bf16 ----
        int m = bid - B0;
        const float4* row = reinterpret_cast<const float4*>(x + (size_t)m * DIN);
        float4 v[3];
        float vm = 0.f;
#pragma unroll
        for (int i = 0; i < 3; ++i) {
            v[i] = row[t + i * 256];
            vm = fmaxf(vm, fmaxf(fmaxf(fabsf(v[i].x), fabsf(v[i].y)),
                                 fmaxf(fabsf(v[i].z), fabsf(v[i].w))));
        }
#pragma unroll
        for (int d = 1; d < 64; d <<= 1) vm = fmaxf(vm, __shfl_xor(vm, d));
        __shared__ float sm[4];
        if ((t & 63) == 0) sm[t >> 6] = vm;
        __syncthreads();
        vm = fmaxf(fmaxf(sm[0], sm[1]), fmaxf(sm[2], sm[3]));
        float s = fmaxf(vm * (1.f / 7.f), 1e-8f);
        float inv = 1.f / s;
        bf16x4* orow = reinterpret_cast<bf16x4*>(xq + (size_t)m * DIN);
#pragma unroll
        for (int i = 0; i < 3; ++i) {
            bf16x4 o;
            o[0] = (bf16_t)(fminf(fmaxf(rintf(v[i].x * inv), -8.f), 7.f) * s);
            o[1] = (bf16_t)(fminf(fmaxf(rintf(v[i].y * inv), -8.f), 7.f) * s);
            o[2] = (bf16_t)(fminf(fmaxf(rintf(v[i].z * inv), -8.f), 7.f) * s);
            o[3] = (bf16_t)(fminf(fmaxf(rintf(v[i].w * inv), -8.f), 7.f) * s);
            orow[t + i * 256] = o;
        }
    } else if (bid < B2) {
        // ---- cast lora_up f32 -> bf16 ----
        size_t idx = (size_t)(bid - B1) * 256 + t;
        float4 v = reinterpret_cast<const float4*>(lu)[idx];
        bf16x4 o;
        o[0] = (bf16_t)v.x; o[1] = (bf16_t)v.y; o[2] = (bf16_t)v.z; o[3] = (bf16_t)v.w;
        reinterpret_cast<bf16x4*>(lub)[idx] = o;
    } else {
        // ---- per-(row, group-of-64) weight int4 fake-quant -> bf16 ----
        // w is read-once: non-temporal load (ext_vector type: builtin requires it)
        size_t idx = (size_t)(bid - B2) * 256 + t;   // f32x4 index
        f32x4 v = __builtin_nontemporal_load(reinterpret_cast<const f32x4*>(w) + idx);
        float vm = fmaxf(fmaxf(fabsf(v[0]), fabsf(v[1])), fmaxf(fabsf(v[2]), fabsf(v[3])));
        vm = fmaxf(vm, __shfl_xor(vm, 1));
        vm = fmaxf(vm, __shfl_xor(vm, 2));
        vm = fmaxf(vm, __shfl_xor(vm, 4));
        vm = fmaxf(vm, __shfl_xor(vm, 8));
        float s = fmaxf(vm * (1.f / 7.f), 1e-8f);
        float inv = 1.f / s;
        bf16x4 o;
        o[0] = (bf16_t)(fminf(fmaxf(rintf(v[0] * inv), -8.f), 7.f) * s);
        o[1] = (bf16_t)(fminf(fmaxf(rintf(v[1] * inv), -8.f), 7.f) * s);
        o[2] = (bf16_t)(fminf(fmaxf(rintf(v[2] * inv), -8.f), 7.f) * s);
        o[3] = (bf16_t)(fminf(fmaxf(rintf(v[3] * inv), -8.f), 7.f) * s);
        reinterpret_cast<bf16x4*>(wq)[idx] = o;
    }
}

// ---------------- K4: fused GEMM (h + gate tiles) + LoRA + GEGLU ------------------
// Measured-best structure (r15: k_gemm ~605 us, MfmaUtil ~50%, 0 conflicts,
// 46% occupancy): 8 waves H/G split, 48KB single-buffer staging, 2 BAR/tile,
// 2 blocks/CU, nt f32x4 coalesced output stream.
__global__ __launch_bounds__(512, 2) void k_gemm(const bf16_t* __restrict__ xq,
                                                 const bf16_t* __restrict__ wq,
                                                 const bf16_t* __restrict__ T,
                                                 const bf16_t* __restrict__ lub,
                                                 float* __restrict__ out) {
    __shared__ __align__(16) char smem[65536];       // staging 48KB; epilogue exch 64KB
    bf16_t* sA = (bf16_t*)smem;                      // [128][64]
    bf16_t* sH = sA + BM * BK;
    bf16_t* sG = sH + BN * BK;

    int tid = threadIdx.x, lane = tid & 63, w = tid >> 6;
    int half = w >> 2;                 // 0 = H, 1 = G
    int wr = (w & 3) >> 1, wc = w & 1;

    // XCD-bijective swizzle (grid 1536 % 8 == 0)
    int nwg = gridDim.x;
    int cpx = nwg >> 3;
    int swz = (blockIdx.x & 7) * cpx + (blockIdx.x >> 3);
    int mt = swz & 31, nt = swz >> 5;  // mt fast: neighbors share B tiles
    int m0 = mt * BM, c0 = nt * BN;

    f32x4 acc[4][4];
#pragma unroll
    for (int i = 0; i < 4; ++i)
#pragma unroll
        for (int j = 0; j < 4; ++j) acc[i][j] = (f32x4){0.f, 0.f, 0.f, 0.f};

    const char* sBb = (const char*)(half ? sG : sH);
    const char* sAb = (const char*)sA;

    for (int k0 = 0; k0 < DIN; k0 += BK) {
        __syncthreads();
        // stage 3 tiles of 128x64 bf16; 1024 16B-chunks each; 512 lanes -> 2 rounds.
#pragma unroll
        for (int r = 0; r < 2; ++r) {
            int chunk = r * 512 + tid;
            int row = chunk >> 3;
            int gc = ((chunk & 7) ^ (row & 7)) * 8;
            int ldsoff = r * 4096 + w * 512;
            GLD16(xq + (size_t)(m0 + row) * DIN + k0 + gc, sA + ldsoff);
            GLD16(wq + (size_t)(c0 + row) * DIN + k0 + gc, sH + ldsoff);
            GLD16(wq + (size_t)(c0 + HALF + row) * DIN + k0 + gc, sG + ldsoff);
        }
        __syncthreads();   // vmcnt(0) drain before barrier

#pragma unroll
        for (int ks = 0; ks < 2; ++ks) {
            int c16 = ks * 4 + (lane >> 4);
            bf16x8 a[4], b[4];
#pragma unroll
            for (int i = 0; i < 4; ++i) {
                int ra = wr * 64 + i * 16 + (lane & 15);
                int rb = wc * 64 + i * 16 + (lane & 15);
                a[i] = *reinterpret_cast<const bf16x8*>(sAb + ra * 128 + ((c16 ^ (ra & 7)) << 4));
                b[i] = *reinterpret_cast<const bf16x8*>(sBb + rb * 128 + ((c16 ^ (rb & 7)) << 4));
            }
#pragma unroll
            for (int m = 0; m < 4; ++m)
#pragma unroll
                for (int n = 0; n < 4; ++n)
                    acc[m][n] = __builtin_amdgcn_mfma_f32_16x16x32_bf16(a[m], b[n], acc[m][n], 0, 0, 0);
        }
    }

    // ---- LoRA correction: one K=32 MFMA per fragment (RANK == 32) ----
    {
        bf16x8 tf[4];
#pragma unroll
        for (int m = 0; m < 4; ++m)
            tf[m] = *reinterpret_cast<const bf16x8*>(
                T + (size_t)(m0 + wr * 64 + m * 16 + (lane & 15)) * 32 + (lane >> 4) * 8);
#pragma unroll
        for (int n = 0; n < 4; ++n) {
            bf16x8 lu = *reinterpret_cast<const bf16x8*>(
                lub + (size_t)(c0 + half * HALF + wc * 64 + n * 16 + (lane & 15)) * 32 + (lane >> 4) * 8);
#pragma unroll
            for (int m = 0; m < 4; ++m)
                acc[m][n] = __builtin_amdgcn_mfma_f32_16x16x32_bf16(tf[m], lu, acc[m][n], 0, 0, 0);
        }
    }

    // ---- GEGLU epilogue: exch gl -> in-place product -> coalesced nt stores ----
    __syncthreads();                    // all LDS staging reads done; reuse smem
    float* exch = (float*)smem;         // [128][128] f32, col XOR-swizzled
    if (half) {
#pragma unroll
        for (int m = 0; m < 4; ++m)
#pragma unroll
            for (int n = 0; n < 4; ++n) {
                int col = wc * 64 + n * 16 + (lane & 15);
#pragma unroll
                for (int r = 0; r < 4; ++r) {
                    int row = wr * 64 + m * 16 + (lane >> 4) * 4 + r;
                    float g = acc[m][n][r];
                    float gl = 0.5f * g * (1.0f + erff(g * 0.70710678118654752f));
                    exch[row * 128 + (col ^ (((row >> 2) & 3) << 4))] = gl;
                }
            }
    }
    __syncthreads();
    if (!half) {
        // in-place: each slot read+written by the same lane only
#pragma unroll
        for (int m = 0; m < 4; ++m)
#pragma unroll
            for (int n = 0; n < 4; ++n) {
                int col = wc * 64 + n * 16 + (lane & 15);
#pragma unroll
                for (int r = 0; r < 4; ++r) {
                    int row = wr * 64 + m * 16 + (lane >> 4) * 4 + r;
                    int sidx = row * 128 + (col ^ (((row >> 2) & 3) << 4));
                    exch[sidx] = acc[m][n][r] * exch[sidx];
                }
            }
    }
    __syncthreads();
    // all 8 waves: stream 64 KB out, 16B/lane coalesced, full-line nt writes
#pragma unroll
    for (int i = 0; i < 8; ++i) {
        int idx = i * 512 + tid;        // f32x4 chunk id, 4096 total
        int row = idx >> 5;             // 32 chunks per 128-col row
        int c4 = idx & 31;
        f32x4 v = *reinterpret_cast<const f32x4*>(
            exch + row * 128 + ((c4 ^ (((row >> 2) & 3) << 2)) << 2));
        __builtin_nontemporal_store(v, reinterpret_cast<f32x4*>(
            out + (size_t)(m0 + row) * HALF + c0 + c4 * 4));
    }
}

extern "C" void kernel_launch(void* const* d_in, const int* in_sizes, int n_in,
                              void* d_out, int out_size, void* d_ws, size_t ws_size,
                              hipStream_t stream) {
    const float* x  = (const float*)d_in[0];   // [1,4096,3072]
    const float* wr = (const float*)d_in[1];   // [24576,3072]
    const float* ld = (const float*)d_in[2];   // [32,3072]
    const float* lu = (const float*)d_in[3];   // [24576,32]
    float* out = (float*)d_out;                // [4096,12288] f32

    bf16_t* xq  = (bf16_t*)d_ws;
    bf16_t* wq  = xq + (size_t)MTOK * DIN;
    bf16_t* T   = wq + (size_t)NOUT * DIN;
    bf16_t* lub = T  + (size_t)MTOK * 32;

    k_prep<<<NB_PREP, 256, 0, stream>>>(x, wr, ld, lu, xq, wq, T, lub);
    k_gemm<<<(MTOK / BM) * (HALF / BN), 512, 0, stream>>>(xq, wq, T, lub, out);
}

// Round 19
// 747.547 us; speedup vs baseline: 1.2352x; 1.0105x over previous
//
#include <hip/hip_runtime.h>
#include <hip/hip_bf16.h>
#include <math.h>

typedef __bf16 bf16_t;
typedef __bf16 bf16x4 __attribute__((ext_vector_type(4)));
typedef __bf16 bf16x8 __attribute__((ext_vector_type(8)));
typedef float  f32x4  __attribute__((ext_vector_type(4)));

#define DIN   3072
#define NOUT  24576
#define HALF  12288
#define MTOK  4096
#define BM    128
#define BN    128
#define BK    64

// fused-prepass block ranges (small kernels first: overlap under quant_w's body)
#define NB_LORA  (MTOK / 8)                       // 512
#define NB_QX    (MTOK)                           // 4096
#define NB_CVT   (NOUT * 32 / 4 / 256)            // 768
#define NB_QW    (NOUT * (DIN / 4) / 512)         // 36864 (2 f32x4 per thread)
#define B0       (NB_LORA)
#define B1       (B0 + NB_QX)
#define B2       (B1 + NB_CVT)
#define NB_PREP  (B2 + NB_QW)

#define GLD16(gp, lp) \
    __builtin_amdgcn_global_load_lds((const __attribute__((address_space(1))) void*)(gp), \
                                     (__attribute__((address_space(3))) void*)(lp), 16, 0, 0)

// ---------------- fused prepass: lora_t | quant_x | cvt_lu | quant_w --------------
__global__ __launch_bounds__(256) void k_prep(const float* __restrict__ x,
                                              const float* __restrict__ w,
                                              const float* __restrict__ ld,
                                              const float* __restrict__ lu,
                                              bf16_t* __restrict__ xq,
                                              bf16_t* __restrict__ wq,
                                              bf16_t* __restrict__ T,
                                              bf16_t* __restrict__ lub) {
    const int bid = blockIdx.x;
    const int t = threadIdx.x;

    if (bid < B0) {
        // ---- T = x @ lora_down^T (full-precision x), 8 tokens x 32 ranks ----
        int r = t & 31;
        int m = bid * 8 + (t >> 5);
        const float4* xr = reinterpret_cast<const float4*>(x + (size_t)m * DIN);
        const float4* lr = reinterpret_cast<const float4*>(ld + (size_t)r * DIN);
        float acc = 0.f;
#pragma unroll 4
        for (int i = 0; i < DIN / 4; ++i) {
            float4 a = xr[i], b = lr[i];
            acc += a.x * b.x + a.y * b.y + a.z * b.z + a.w * b.w;
        }
        T[(size_t)m * 32 + r] = (bf16_t)acc;
    } else if (bid < B1) {
        // ---- per-token activation int4 fake-quant -> bf16 ----
        int m = bid - B0;
        const float4* row = reinterpret_cast<const float4*>(x + (size_t)m * DIN);
        float4 v[3];
        float vm = 0.f;
#pragma unroll
        for (int i = 0; i < 3; ++i) {
            v[i] = row[t + i * 256];
            vm = fmaxf(vm, fmaxf(fmaxf(fabsf(v[i].x), fabsf(v[i].y)),
                                 fmaxf(fabsf(v[i].z), fabsf(v[i].w))));
        }
#pragma unroll
        for (int d = 1; d < 64; d <<= 1) vm = fmaxf(vm, __shfl_xor(vm, d));
        __shared__ float sm[4];
        if ((t & 63) == 0) sm[t >> 6] = vm;
        __syncthreads();
        vm = fmaxf(fmaxf(sm[0], sm[1]), fmaxf(sm[2], sm[3]));
        float s = fmaxf(vm * (1.f / 7.f), 1e-8f);
        float inv = 1.f / s;
        bf16x4* orow = reinterpret_cast<bf16x4*>(xq + (size_t)m * DIN);
#pragma unroll
        for (int i = 0; i < 3; ++i) {
            bf16x4 o;
            o[0] = (bf16_t)(fminf(fmaxf(rintf(v[i].x * inv), -8.f), 7.f) * s);
            o[1] = (bf16_t)(fminf(fmaxf(rintf(v[i].y * inv), -8.f), 7.f) * s);
            o[2] = (bf16_t)(fminf(fmaxf(rintf(v[i].z * inv), -8.f), 7.f) * s);
            o[3] = (bf16_t)(fminf(fmaxf(rintf(v[i].w * inv), -8.f), 7.f) * s);
            orow[t + i * 256] = o;
        }
    } else if (bid < B2) {
        // ---- cast lora_up f32 -> bf16 ----
        size_t idx = (size_t)(bid - B1) * 256 + t;
        float4 v = reinterpret_cast<const float4*>(lu)[idx];
        bf16x4 o;
        o[0] = (bf16_t)v.x; o[1] = (bf16_t)v.y; o[2] = (bf16_t)v.z; o[3] = (bf16_t)v.w;
        reinterpret_cast<bf16x4*>(lub)[idx] = o;
    } else {
        // ---- per-(row, group-of-64) weight int4 fake-quant -> bf16 ----
        // 2 chunks/thread (32 B/lane loads); both chunk sets group-aligned
        // (chunk c: lanes 16k..16k+15 cover one 64-elem group; +256 preserves it).
        size_t base = (size_t)(bid - B2) * 512 + t;
#pragma unroll
        for (int h = 0; h < 2; ++h) {
            size_t idx = base + h * 256;             // f32x4 index
            f32x4 v = __builtin_nontemporal_load(reinterpret_cast<const f32x4*>(w) + idx);
            float vm = fmaxf(fmaxf(fabsf(v[0]), fabsf(v[1])), fmaxf(fabsf(v[2]), fabsf(v[3])));
            vm = fmaxf(vm, __shfl_xor(vm, 1));
            vm = fmaxf(vm, __shfl_xor(vm, 2));
            vm = fmaxf(vm, __shfl_xor(vm, 4));
            vm = fmaxf(vm, __shfl_xor(vm, 8));
            float s = fmaxf(vm * (1.f / 7.f), 1e-8f);
            float inv = 1.f / s;
            bf16x4 o;
            o[0] = (bf16_t)(fminf(fmaxf(rintf(v[0] * inv), -8.f), 7.f) * s);
            o[1] = (bf16_t)(fminf(fmaxf(rintf(v[1] * inv), -8.f), 7.f) * s);
            o[2] = (bf16_t)(fminf(fmaxf(rintf(v[2] * inv), -8.f), 7.f) * s);
            o[3] = (bf16_t)(fminf(fmaxf(rintf(v[3] * inv), -8.f), 7.f) * s);
            reinterpret_cast<bf16x4*>(wq)[idx] = o;
        }
    }
}

// ---------------- K4: fused GEMM (h + gate tiles) + LoRA + GEGLU ------------------
// r15 structure (measured best: k_gemm ~600 us, MfmaUtil ~49%, 0 conflicts,
// 46% occupancy) with L2/L3-aware block ordering: per-XCD chunk of 384 blocks
// decomposed into 4 groups of (8 mt x 12 nt). Within a group the xq footprint
// is 6 MB (L2/L3-hot) and the XCD's 12 wq panels are L2-private -> staged loads
// hit cache -> shorter vmcnt(0) drains (r14 mechanism, 2nd application).
__global__ __launch_bounds__(512, 2) void k_gemm(const bf16_t* __restrict__ xq,
                                                 const bf16_t* __restrict__ wq,
                                                 const bf16_t* __restrict__ T,
                                                 const bf16_t* __restrict__ lub,
                                                 float* __restrict__ out) {
    __shared__ __align__(16) char smem[65536];       // staging 48KB; epilogue exch 64KB
    bf16_t* sA = (bf16_t*)smem;                      // [128][64]
    bf16_t* sH = sA + BM * BK;
    bf16_t* sG = sH + BN * BK;

    int tid = threadIdx.x, lane = tid & 63, w = tid >> 6;
    int half = w >> 2;                 // 0 = H, 1 = G
    int wr = (w & 3) >> 1, wc = w & 1;

    // XCD-bijective + grouped ordering. grid 3072 = 8 xcd x 4 grp x (8 mt x 12 nt).
    int xcd = (int)blockIdx.x & 7;
    int lid = (int)blockIdx.x >> 3;    // [0,384) per XCD
    int grp = lid / 96;
    int wl  = lid - grp * 96;
    int mt  = grp * 8 + (wl & 7);      // [0,32)
    int nt  = xcd * 12 + (wl >> 3);    // [0,96)
    int m0 = mt * BM, c0 = nt * BN;

    f32x4 acc[4][4];
#pragma unroll
    for (int i = 0; i < 4; ++i)
#pragma unroll
        for (int j = 0; j < 4; ++j) acc[i][j] = (f32x4){0.f, 0.f, 0.f, 0.f};

    const char* sBb = (const char*)(half ? sG : sH);
    const char* sAb = (const char*)sA;

    for (int k0 = 0; k0 < DIN; k0 += BK) {
        __syncthreads();
        // stage 3 tiles of 128x64 bf16; 1024 16B-chunks each; 512 lanes -> 2 rounds.
#pragma unroll
        for (int r = 0; r < 2; ++r) {
            int chunk = r * 512 + tid;
            int row = chunk >> 3;
            int gc = ((chunk & 7) ^ (row & 7)) * 8;
            int ldsoff = r * 4096 + w * 512;
            GLD16(xq + (size_t)(m0 + row) * DIN + k0 + gc, sA + ldsoff);
            GLD16(wq + (size_t)(c0 + row) * DIN + k0 + gc, sH + ldsoff);
            GLD16(wq + (size_t)(c0 + HALF + row) * DIN + k0 + gc, sG + ldsoff);
        }
        __syncthreads();   // vmcnt(0) drain before barrier

#pragma unroll
        for (int ks = 0; ks < 2; ++ks) {
            int c16 = ks * 4 + (lane >> 4);
            bf16x8 a[4], b[4];
#pragma unroll
            for (int i = 0; i < 4; ++i) {
                int ra = wr * 64 + i * 16 + (lane & 15);
                int rb = wc * 64 + i * 16 + (lane & 15);
                a[i] = *reinterpret_cast<const bf16x8*>(sAb + ra * 128 + ((c16 ^ (ra & 7)) << 4));
                b[i] = *reinterpret_cast<const bf16x8*>(sBb + rb * 128 + ((c16 ^ (rb & 7)) << 4));
            }
#pragma unroll
            for (int m = 0; m < 4; ++m)
#pragma unroll
                for (int n = 0; n < 4; ++n)
                    acc[m][n] = __builtin_amdgcn_mfma_f32_16x16x32_bf16(a[m], b[n], acc[m][n], 0, 0, 0);
        }
    }

    // ---- LoRA correction: one K=32 MFMA per fragment (RANK == 32) ----
    {
        bf16x8 tf[4];
#pragma unroll
        for (int m = 0; m < 4; ++m)
            tf[m] = *reinterpret_cast<const bf16x8*>(
                T + (size_t)(m0 + wr * 64 + m * 16 + (lane & 15)) * 32 + (lane >> 4) * 8);
#pragma unroll
        for (int n = 0; n < 4; ++n) {
            bf16x8 lu = *reinterpret_cast<const bf16x8*>(
                lub + (size_t)(c0 + half * HALF + wc * 64 + n * 16 + (lane & 15)) * 32 + (lane >> 4) * 8);
#pragma unroll
            for (int m = 0; m < 4; ++m)
                acc[m][n] = __builtin_amdgcn_mfma_f32_16x16x32_bf16(tf[m], lu, acc[m][n], 0, 0, 0);
        }
    }

    // ---- GEGLU epilogue: exch gl -> in-place product -> coalesced nt stores ----
    __syncthreads();                    // all LDS staging reads done; reuse smem
    float* exch = (float*)smem;         // [128][128] f32, col XOR-swizzled
    if (half) {
#pragma unroll
        for (int m = 0; m < 4; ++m)
#pragma unroll
            for (int n = 0; n < 4; ++n) {
                int col = wc * 64 + n * 16 + (lane & 15);
#pragma unroll
                for (int r = 0; r < 4; ++r) {
                    int row = wr * 64 + m * 16 + (lane >> 4) * 4 + r;
                    float g = acc[m][n][r];
                    float gl = 0.5f * g * (1.0f + erff(g * 0.70710678118654752f));
                    exch[row * 128 + (col ^ (((row >> 2) & 3) << 4))] = gl;
                }
            }
    }
    __syncthreads();
    if (!half) {
        // in-place: each slot read+written by the same lane only
#pragma unroll
        for (int m = 0; m < 4; ++m)
#pragma unroll
            for (int n = 0; n < 4; ++n) {
                int col = wc * 64 + n * 16 + (lane & 15);
#pragma unroll
                for (int r = 0; r < 4; ++r) {
                    int row = wr * 64 + m * 16 + (lane >> 4) * 4 + r;
                    int sidx = row * 128 + (col ^ (((row >> 2) & 3) << 4));
                    exch[sidx] = acc[m][n][r] * exch[sidx];
                }
            }
    }
    __syncthreads();
    // all 8 waves: stream 64 KB out, 16B/lane coalesced, full-line nt writes
#pragma unroll
    for (int i = 0; i < 8; ++i) {
        int idx = i * 512 + tid;        // f32x4 chunk id, 4096 total
        int row = idx >> 5;             // 32 chunks per 128-col row
        int c4 = idx & 31;
        f32x4 v = *reinterpret_cast<const f32x4*>(
            exch + row * 128 + ((c4 ^ (((row >> 2) & 3) << 2)) << 2));
        __builtin_nontemporal_store(v, reinterpret_cast<f32x4*>(
            out + (size_t)(m0 + row) * HALF + c0 + c4 * 4));
    }
}

extern "C" void kernel_launch(void* const* d_in, const int* in_sizes, int n_in,
                              void* d_out, int out_size, void* d_ws, size_t ws_size,
                              hipStream_t stream) {
    const float* x  = (const float*)d_in[0];   // [1,4096,3072]
    const float* wr = (const float*)d_in[1];   // [24576,3072]
    const float* ld = (const float*)d_in[2];   // [32,3072]
    const float* lu = (const float*)d_in[3];   // [24576,32]
    float* out = (float*)d_out;                // [4096,12288] f32

    bf16_t* xq  = (bf16_t*)d_ws;
    bf16_t* wq  = xq + (size_t)MTOK * DIN;
    bf16_t* T   = wq + (size_t)NOUT * DIN;
    bf16_t* lub = T  + (size_t)MTOK * 32;

    k_prep<<<NB_PREP, 256, 0, stream>>>(x, wr, ld, lu, xq, wq, T, lub);
    k_gemm<<<(MTOK / BM) * (HALF / BN), 512, 0, stream>>>(xq, wq, T, lub, out);
}